// Round 11
// baseline (231.330 us; speedup 1.0000x reference)
//
#include <hip/hip_runtime.h>
#include <math.h>

#define B_ 16
#define C_ 64
#define HW_ 4096          // 64*64
#define PHW_ 1024         // pooled 32*32

typedef __attribute__((ext_vector_type(8))) short bf8;    // 8 bf16 = 4 VGPR (MFMA A/B)
typedef __attribute__((ext_vector_type(16))) float fv16;  // 16 f32 (MFMA C/D 32x32)

union FU { bf8 v; unsigned u[4]; };

__device__ inline unsigned short f2bf(float f) {          // RNE f32->bf16
    unsigned u = __float_as_uint(f);
    return (unsigned short)((u + 0x7FFFu + ((u >> 16) & 1u)) >> 16);
}
__device__ inline unsigned packbf(float a, float b) {     // two f32 -> packed bf16x2 (RNE)
    return (unsigned)f2bf(a) | ((unsigned)f2bf(b) << 16);
}
__device__ inline unsigned packtr(float a, float b) {     // truncating pack (fast path)
    return (__float_as_uint(a) >> 16) | (__float_as_uint(b) & 0xFFFF0000u);
}

// ---------------------------------------------------------------------------
// Kernel 1: MFMA conv (UNCHANGED from R8 — measured warm ~7.4 us in R10).
// ---------------------------------------------------------------------------
__global__ __launch_bounds__(256) void conv_stage(
    const float* __restrict__ x,
    const float* __restrict__ Wt,   // [8][64]
    const float* __restrict__ Wp,   // [8][64]
    const float* __restrict__ Wg,   // [32][64]
    float* __restrict__ theta,      // [B][8][HW]
    unsigned short* __restrict__ phi_pack,
    unsigned short* __restrict__ g_pack)
{
    __shared__ float sx[64][128];        // 32 KB, [c][px]
    __shared__ float poolh[2][40][33];   // per-image-row hmax, 10.3 KB

    const int t  = threadIdx.x;
    const int b  = blockIdx.x >> 5;
    const int h2 = blockIdx.x & 31;      // pooled row (image rows 2h2, 2h2+1)

    const float* xbase = x + (size_t)b * C_ * HW_ + h2 * 128;
    for (int f = t; f < 2048; f += 256) {
        int c = f >> 5, j4 = f & 31;
        *(float4*)&sx[c][j4 * 4] = *(const float4*)&xbase[(size_t)c * HW_ + j4 * 4];
    }

    const int wv = t >> 6, lane = t & 63, lo = lane & 31, hi = lane >> 5;

    FU wa[2][4];
    {
        const float* r0 = (lo < 8)  ? (Wt + lo * 64)
                        : (lo < 16) ? (Wp + (lo - 8) * 64)
                                    : (Wg + (lo - 16) * 64);
        const float* r1 = Wg + ((lo < 16) ? (16 + lo) : 0) * 64;
#pragma unroll
        for (int cs = 0; cs < 4; cs++) {
            const int c0 = cs * 16 + hi * 8;
            float4 a0 = *(const float4*)&r0[c0];
            float4 b0 = *(const float4*)&r0[c0 + 4];
            wa[0][cs].u[0] = packbf(a0.x, a0.y); wa[0][cs].u[1] = packbf(a0.z, a0.w);
            wa[0][cs].u[2] = packbf(b0.x, b0.y); wa[0][cs].u[3] = packbf(b0.z, b0.w);
            float4 a1 = *(const float4*)&r1[c0];
            float4 b1 = *(const float4*)&r1[c0 + 4];
            if (lo >= 16) { a1 = make_float4(0.f,0.f,0.f,0.f); b1 = make_float4(0.f,0.f,0.f,0.f); }
            wa[1][cs].u[0] = packbf(a1.x, a1.y); wa[1][cs].u[1] = packbf(a1.z, a1.w);
            wa[1][cs].u[2] = packbf(b1.x, b1.y); wa[1][cs].u[3] = packbf(b1.z, b1.w);
        }
    }
    __syncthreads();

    fv16 acc0, acc1;
#pragma unroll
    for (int r = 0; r < 16; r++) { acc0[r] = 0.f; acc1[r] = 0.f; }

    const int px = wv * 32 + lo;         // local pixel 0..127
#pragma unroll
    for (int cs = 0; cs < 4; cs++) {
        const float* sp = &sx[cs * 16 + hi * 8][px];
        float v[8];
#pragma unroll
        for (int j = 0; j < 8; j++) v[j] = sp[j * 128];
        FU xb;
        xb.u[0] = packbf(v[0], v[1]); xb.u[1] = packbf(v[2], v[3]);
        xb.u[2] = packbf(v[4], v[5]); xb.u[3] = packbf(v[6], v[7]);
        acc0 = __builtin_amdgcn_mfma_f32_32x32x16_bf16(wa[0][cs].v, xb.v, acc0, 0, 0, 0);
        acc1 = __builtin_amdgcn_mfma_f32_32x32x16_bf16(wa[1][cs].v, xb.v, acc1, 0, 0, 0);
    }

    {
        float* tp = theta + (size_t)b * 8 * HW_ + h2 * 128 + px;
#pragma unroll
        for (int r = 0; r < 4; r++) tp[(size_t)(r + 4 * hi) * HW_] = acc0[r];
    }

    const int prow = wv >> 1;
    const int pcol = (wv & 1) * 16 + (lo >> 1);
#pragma unroll
    for (int r = 4; r < 16; r++) {              // tile0: ch 8..31 -> pch 0..23
        float vv = acc0[r];
        float hm = fmaxf(vv, __shfl_xor(vv, 1));
        if ((lane & 1) == 0) {
            int m = (r & 3) + 8 * (r >> 2) + 4 * hi;   // 8..31
            poolh[prow][m - 8][pcol] = hm;
        }
    }
#pragma unroll
    for (int r = 0; r < 8; r++) {               // tile1: ch 32..47 -> pch 24..39
        float vv = acc1[r];
        float hm = fmaxf(vv, __shfl_xor(vv, 1));
        if ((lane & 1) == 0) {
            int m1 = (r & 3) + 8 * (r >> 2) + 4 * hi;  // 0..15
            poolh[prow][24 + m1][pcol] = hm;
        }
    }
    __syncthreads();

    if (t < 64) {
        unsigned u0 = 0, u1 = 0, u2 = 0, u3 = 0;
        if (t < 32) {
            float v[8];
#pragma unroll
            for (int j = 0; j < 8; j++)
                v[j] = fmaxf(poolh[0][j][t], poolh[1][j][t]);
            u0 = packbf(v[0], v[1]); u1 = packbf(v[2], v[3]);
            u2 = packbf(v[4], v[5]); u3 = packbf(v[6], v[7]);
        }
        uint4 pkt = make_uint4(u0, u1, u2, u3);
        *(uint4*)(phi_pack + ((size_t)((b * 32 + h2) * 64 + t)) * 8) = pkt;
    } else if (t < 192) {
        const int tt  = t - 64;
        const int ktl = tt >> 6;
        const int ln  = tt & 63;
        const int c   = ln & 31;
        const int hh  = ln >> 5;
        float v[8];
#pragma unroll
        for (int j = 0; j < 8; j++) {
            int p = ktl * 16 + hh * 8 + j;
            v[j] = fmaxf(poolh[0][8 + c][p], poolh[1][8 + c][p]);
        }
        uint4 pkt = make_uint4(packbf(v[0], v[1]), packbf(v[2], v[3]),
                               packbf(v[4], v[5]), packbf(v[6], v[7]));
        *(uint4*)(g_pack + ((size_t)((b * 64 + h2 * 2 + ktl) * 64 + ln)) * 8) = pkt;
    }
}

// ---------------------------------------------------------------------------
// Kernel 2: MFMA flash attention. R11: explicit software pipeline — fully
// unrolled K-loop with iteration i+1's pa/ga loads issued before processing
// iteration i (global-load latency hides under exp/pack/MFMA instead of
// heading each iteration). R9's xv[16] prefetch and NT stores (both measured
// neutral) are dropped to free the registers for the pipeline; epilogue is
// back to R8 form (regular x loads + regular out stores — also defers out's
// writeback past the timed window).
// ---------------------------------------------------------------------------
__global__ __launch_bounds__(256, 4) void attn_mfma(
    const float* __restrict__ theta_g,              // [B][8][HW]
    const unsigned short* __restrict__ phi_pack,
    const unsigned short* __restrict__ g_pack,
    const float* __restrict__ Wa,                   // [64][32]
    const float* __restrict__ x,
    const float* __restrict__ sigma,
    float* __restrict__ out)
{
    __shared__ float comb[4][64][17];

    const int t = threadIdx.x, wave = t >> 6, lane = t & 63;
    const int lo = lane & 31, hi = lane >> 5;
    const int qtile = blockIdx.x * 2 + (wave >> 1);
    const int khalf = wave & 1;
    const int b = qtile >> 7, qt = qtile & 127;
    const int qg = qt * 32 + lo;                    // this lane's query column

    FU tb; tb.u[0] = tb.u[1] = tb.u[2] = tb.u[3] = 0;
    if (hi == 0) {
        const float LOG2E = 1.4426950408889634f;
        float tv[8];
#pragma unroll
        for (int j = 0; j < 8; j++)
            tv[j] = theta_g[(((size_t)b * 8 + j) << 12) + qg] * LOG2E;
        tb.u[0] = packbf(tv[0], tv[1]); tb.u[1] = packbf(tv[2], tv[3]);
        tb.u[2] = packbf(tv[4], tv[5]); tb.u[3] = packbf(tv[6], tv[7]);
    }

    fv16 zf, acc;
#pragma unroll
    for (int r = 0; r < 16; r++) { zf[r] = 0.f; acc[r] = 0.f; }
    float ps = 0.f;

    const int kt0 = khalf * 16;
    const unsigned short* phip = phi_pack + ((size_t)((b * 32 + kt0) * 64 + lane)) * 8;
    const unsigned short* gp   = g_pack   + ((size_t)((b * 64 + kt0 * 2) * 64 + lane)) * 8;

    // software pipeline: stage 0 loads issued before the loop
    FU pa, ga0, ga1;
    pa.v  = *(const bf8*)(phip);
    ga0.v = *(const bf8*)(gp);
    ga1.v = *(const bf8*)(gp + 512);

#pragma unroll
    for (int i = 0; i < 16; i++) {
        // prefetch next iteration's fragments (compile-time guard: full unroll)
        FU paN, ga0N, ga1N;
        if (i < 15) {
            paN.v  = *(const bf8*)(phip + (size_t)(i + 1) * 512);
            ga0N.v = *(const bf8*)(gp + (size_t)(i + 1) * 1024);
            ga1N.v = *(const bf8*)(gp + (size_t)(i + 1) * 1024 + 512);
        }

        fv16 s = __builtin_amdgcn_mfma_f32_32x32x16_bf16(pa.v, tb.v, zf, 0, 0, 0);

        {   // half A: C-regs 0..7 -> PV B-frag for ga0
            unsigned pk[4], qk[4];
#pragma unroll
            for (int u = 0; u < 4; u++) {
                float p0 = __builtin_amdgcn_exp2f(s[2 * u]);
                float p1 = __builtin_amdgcn_exp2f(s[2 * u + 1]);
                ps += p0 + p1;
                pk[u] = packtr(p0, p1);
            }
#pragma unroll
            for (int u = 0; u < 4; u++) qk[u] = (unsigned)__shfl_xor((int)pk[u], 32);
            FU pb;
            pb.u[0] = hi ? qk[2] : pk[0]; pb.u[1] = hi ? qk[3] : pk[1];
            pb.u[2] = hi ? pk[2] : qk[0]; pb.u[3] = hi ? pk[3] : qk[1];
            acc = __builtin_amdgcn_mfma_f32_32x32x16_bf16(ga0.v, pb.v, acc, 0, 0, 0);
        }
        {   // half B: C-regs 8..15 -> PV B-frag for ga1
            unsigned pk[4], qk[4];
#pragma unroll
            for (int u = 0; u < 4; u++) {
                float p0 = __builtin_amdgcn_exp2f(s[8 + 2 * u]);
                float p1 = __builtin_amdgcn_exp2f(s[9 + 2 * u]);
                ps += p0 + p1;
                pk[u] = packtr(p0, p1);
            }
#pragma unroll
            for (int u = 0; u < 4; u++) qk[u] = (unsigned)__shfl_xor((int)pk[u], 32);
            FU pb;
            pb.u[0] = hi ? qk[2] : pk[0]; pb.u[1] = hi ? qk[3] : pk[1];
            pb.u[2] = hi ? pk[2] : qk[0]; pb.u[3] = hi ? pk[3] : qk[1];
            acc = __builtin_amdgcn_mfma_f32_32x32x16_bf16(ga1.v, pb.v, acc, 0, 0, 0);
        }

        pa = paN; ga0 = ga0N; ga1 = ga1N;   // rotate pipeline
    }

#pragma unroll
    for (int r = 0; r < 16; r++) comb[wave][lane][r] = acc[r];
    comb[wave][lane][16] = ps;
    __syncthreads();
    const int pw = wave ^ 1;
#pragma unroll
    for (int r = 0; r < 16; r++) acc[r] += comb[pw][lane][r];
    ps += comb[pw][lane][16];

    float lsum = ps + __shfl_xor(ps, 32);
    float inv = 1.f / lsum;

    float on[16];
#pragma unroll
    for (int r = 0; r < 16; r++) on[r] = acc[r] * inv;
    unsigned pk[8], qk[8];
#pragma unroll
    for (int i = 0; i < 8; i++) pk[i] = packtr(on[2 * i], on[2 * i + 1]);
#pragma unroll
    for (int i = 0; i < 8; i++) qk[i] = (unsigned)__shfl_xor((int)pk[i], 32);
    FU ob0, ob1;
    ob0.u[0] = hi ? qk[2] : pk[0]; ob0.u[1] = hi ? qk[3] : pk[1];
    ob0.u[2] = hi ? pk[2] : qk[0]; ob0.u[3] = hi ? pk[3] : qk[1];
    ob1.u[0] = hi ? qk[6] : pk[4]; ob1.u[1] = hi ? qk[7] : pk[5];
    ob1.u[2] = hi ? pk[6] : qk[4]; ob1.u[3] = hi ? pk[7] : qk[5];

    FU wa0, wa1;
    {
        const float* wr = Wa + (khalf * 32 + lo) * 32;
#pragma unroll
        for (int ktw = 0; ktw < 2; ktw++) {
            float w8[8];
#pragma unroll
            for (int j = 0; j < 8; j++) w8[j] = wr[ktw * 16 + hi * 8 + j];
            FU f;
            f.u[0] = packbf(w8[0], w8[1]); f.u[1] = packbf(w8[2], w8[3]);
            f.u[2] = packbf(w8[4], w8[5]); f.u[3] = packbf(w8[6], w8[7]);
            if (ktw == 0) wa0 = f; else wa1 = f;
        }
    }
    fv16 d2 = __builtin_amdgcn_mfma_f32_32x32x16_bf16(wa0.v, ob0.v, zf, 0, 0, 0);
    d2 = __builtin_amdgcn_mfma_f32_32x32x16_bf16(wa1.v, ob1.v, d2, 0, 0, 0);

    const float sig = sigma[0];
#pragma unroll
    for (int r = 0; r < 16; r++) {
        int row = (r & 3) + ((r >> 2) << 3) + (hi << 2);
        int o = khalf * 32 + row;
        size_t idx = (((size_t)b * 64 + o) << 12) + qg;
        out[idx] = x[idx] + sig * d2[r];
    }
}

// ---------------------------------------------------------------------------
extern "C" void kernel_launch(void* const* d_in, const int* in_sizes, int n_in,
                              void* d_out, int out_size, void* d_ws, size_t ws_size,
                              hipStream_t stream) {
    const float* x     = (const float*)d_in[0];
    const float* Wt    = (const float*)d_in[1];
    const float* Wp    = (const float*)d_in[2];
    const float* Wg    = (const float*)d_in[3];
    const float* Wa    = (const float*)d_in[4];
    const float* sigma = (const float*)d_in[5];
    float* out = (float*)d_out;

    // ws layout: theta fp32 (2 MB) | phi_pack bf16 (512 KB) | g_pack bf16 (1 MB)
    float* theta = (float*)d_ws;                                  // 524288 floats
    unsigned short* phi_pack = (unsigned short*)(theta + (size_t)B_ * 8 * HW_);
    unsigned short* g_pack   = phi_pack + (size_t)B_ * 32 * 64 * 8;

    conv_stage<<<512, 256, 0, stream>>>(x, Wt, Wp, Wg, theta, phi_pack, g_pack);
    attn_mfma<<<1024, 256, 0, stream>>>(theta, phi_pack, g_pack, Wa, x, sigma, out);
}

// Round 12
// 99.581 us; speedup vs baseline: 2.3230x; 2.3230x over previous
//
#include <hip/hip_runtime.h>
#include <math.h>

#define B_ 16
#define C_ 64
#define HW_ 4096          // 64*64
#define PHW_ 1024         // pooled 32*32

typedef __attribute__((ext_vector_type(8))) short bf8;    // 8 bf16 = 4 VGPR (MFMA A/B)
typedef __attribute__((ext_vector_type(16))) float fv16;  // 16 f32 (MFMA C/D 32x32)

union FU { bf8 v; unsigned u[4]; };

__device__ inline unsigned short f2bf(float f) {          // RNE f32->bf16
    unsigned u = __float_as_uint(f);
    return (unsigned short)((u + 0x7FFFu + ((u >> 16) & 1u)) >> 16);
}
__device__ inline unsigned packbf(float a, float b) {     // two f32 -> packed bf16x2 (RNE)
    return (unsigned)f2bf(a) | ((unsigned)f2bf(b) << 16);
}
__device__ inline unsigned packtr(float a, float b) {     // truncating pack (fast path)
    return (__float_as_uint(a) >> 16) | (__float_as_uint(b) & 0xFFFF0000u);
}

// ---------------------------------------------------------------------------
// Kernel 1: MFMA conv (R8 version — measured warm ~7.4 us in R10).
// ---------------------------------------------------------------------------
__global__ __launch_bounds__(256) void conv_stage(
    const float* __restrict__ x,
    const float* __restrict__ Wt,   // [8][64]
    const float* __restrict__ Wp,   // [8][64]
    const float* __restrict__ Wg,   // [32][64]
    float* __restrict__ theta,      // [B][8][HW]
    unsigned short* __restrict__ phi_pack,
    unsigned short* __restrict__ g_pack)
{
    __shared__ float sx[64][128];        // 32 KB, [c][px]
    __shared__ float poolh[2][40][33];   // per-image-row hmax, 10.3 KB

    const int t  = threadIdx.x;
    const int b  = blockIdx.x >> 5;
    const int h2 = blockIdx.x & 31;      // pooled row (image rows 2h2, 2h2+1)

    const float* xbase = x + (size_t)b * C_ * HW_ + h2 * 128;
    for (int f = t; f < 2048; f += 256) {
        int c = f >> 5, j4 = f & 31;
        *(float4*)&sx[c][j4 * 4] = *(const float4*)&xbase[(size_t)c * HW_ + j4 * 4];
    }

    const int wv = t >> 6, lane = t & 63, lo = lane & 31, hi = lane >> 5;

    FU wa[2][4];
    {
        const float* r0 = (lo < 8)  ? (Wt + lo * 64)
                        : (lo < 16) ? (Wp + (lo - 8) * 64)
                                    : (Wg + (lo - 16) * 64);
        const float* r1 = Wg + ((lo < 16) ? (16 + lo) : 0) * 64;
#pragma unroll
        for (int cs = 0; cs < 4; cs++) {
            const int c0 = cs * 16 + hi * 8;
            float4 a0 = *(const float4*)&r0[c0];
            float4 b0 = *(const float4*)&r0[c0 + 4];
            wa[0][cs].u[0] = packbf(a0.x, a0.y); wa[0][cs].u[1] = packbf(a0.z, a0.w);
            wa[0][cs].u[2] = packbf(b0.x, b0.y); wa[0][cs].u[3] = packbf(b0.z, b0.w);
            float4 a1 = *(const float4*)&r1[c0];
            float4 b1 = *(const float4*)&r1[c0 + 4];
            if (lo >= 16) { a1 = make_float4(0.f,0.f,0.f,0.f); b1 = make_float4(0.f,0.f,0.f,0.f); }
            wa[1][cs].u[0] = packbf(a1.x, a1.y); wa[1][cs].u[1] = packbf(a1.z, a1.w);
            wa[1][cs].u[2] = packbf(b1.x, b1.y); wa[1][cs].u[3] = packbf(b1.z, b1.w);
        }
    }
    __syncthreads();

    fv16 acc0, acc1;
#pragma unroll
    for (int r = 0; r < 16; r++) { acc0[r] = 0.f; acc1[r] = 0.f; }

    const int px = wv * 32 + lo;         // local pixel 0..127
#pragma unroll
    for (int cs = 0; cs < 4; cs++) {
        const float* sp = &sx[cs * 16 + hi * 8][px];
        float v[8];
#pragma unroll
        for (int j = 0; j < 8; j++) v[j] = sp[j * 128];
        FU xb;
        xb.u[0] = packbf(v[0], v[1]); xb.u[1] = packbf(v[2], v[3]);
        xb.u[2] = packbf(v[4], v[5]); xb.u[3] = packbf(v[6], v[7]);
        acc0 = __builtin_amdgcn_mfma_f32_32x32x16_bf16(wa[0][cs].v, xb.v, acc0, 0, 0, 0);
        acc1 = __builtin_amdgcn_mfma_f32_32x32x16_bf16(wa[1][cs].v, xb.v, acc1, 0, 0, 0);
    }

    {
        float* tp = theta + (size_t)b * 8 * HW_ + h2 * 128 + px;
#pragma unroll
        for (int r = 0; r < 4; r++) tp[(size_t)(r + 4 * hi) * HW_] = acc0[r];
    }

    const int prow = wv >> 1;
    const int pcol = (wv & 1) * 16 + (lo >> 1);
#pragma unroll
    for (int r = 4; r < 16; r++) {              // tile0: ch 8..31 -> pch 0..23
        float vv = acc0[r];
        float hm = fmaxf(vv, __shfl_xor(vv, 1));
        if ((lane & 1) == 0) {
            int m = (r & 3) + 8 * (r >> 2) + 4 * hi;   // 8..31
            poolh[prow][m - 8][pcol] = hm;
        }
    }
#pragma unroll
    for (int r = 0; r < 8; r++) {               // tile1: ch 32..47 -> pch 24..39
        float vv = acc1[r];
        float hm = fmaxf(vv, __shfl_xor(vv, 1));
        if ((lane & 1) == 0) {
            int m1 = (r & 3) + 8 * (r >> 2) + 4 * hi;  // 0..15
            poolh[prow][24 + m1][pcol] = hm;
        }
    }
    __syncthreads();

    if (t < 64) {
        unsigned u0 = 0, u1 = 0, u2 = 0, u3 = 0;
        if (t < 32) {
            float v[8];
#pragma unroll
            for (int j = 0; j < 8; j++)
                v[j] = fmaxf(poolh[0][j][t], poolh[1][j][t]);
            u0 = packbf(v[0], v[1]); u1 = packbf(v[2], v[3]);
            u2 = packbf(v[4], v[5]); u3 = packbf(v[6], v[7]);
        }
        uint4 pkt = make_uint4(u0, u1, u2, u3);
        *(uint4*)(phi_pack + ((size_t)((b * 32 + h2) * 64 + t)) * 8) = pkt;
    } else if (t < 192) {
        const int tt  = t - 64;
        const int ktl = tt >> 6;
        const int ln  = tt & 63;
        const int c   = ln & 31;
        const int hh  = ln >> 5;
        float v[8];
#pragma unroll
        for (int j = 0; j < 8; j++) {
            int p = ktl * 16 + hh * 8 + j;
            v[j] = fmaxf(poolh[0][8 + c][p], poolh[1][8 + c][p]);
        }
        uint4 pkt = make_uint4(packbf(v[0], v[1]), packbf(v[2], v[3]),
                               packbf(v[4], v[5]), packbf(v[6], v[7]));
        *(uint4*)(g_pack + ((size_t)((b * 64 + h2 * 2 + ktl) * 64 + ln)) * 8) = pkt;
    }
}

// ---------------------------------------------------------------------------
// Kernel 2: MFMA flash attention — REVERTED to the R5/R8 form (simple
// #pragma unroll 2 K-loop, no manual pipeline, no xv prefetch, no NT stores).
// R11's hand pipeline (full unroll + conditional prefetch + register
// rotation) forced a pathological 64-VGPR allocation with ~400 MB of scratch
// spill traffic per launch (FETCH 172 MB / WRITE 233 MB, MfmaUtil 1.9%) —
// 135 us vs this version's 17.5 us warm. At 4 waves/SIMD the implicit TLP
// already hides the pack-load latency; do not hand-pipeline this loop.
// ---------------------------------------------------------------------------
__global__ __launch_bounds__(256, 4) void attn_mfma(
    const float* __restrict__ theta_g,              // [B][8][HW]
    const unsigned short* __restrict__ phi_pack,
    const unsigned short* __restrict__ g_pack,
    const float* __restrict__ Wa,                   // [64][32]
    const float* __restrict__ x,
    const float* __restrict__ sigma,
    float* __restrict__ out)
{
    __shared__ float comb[4][64][17];

    const int t = threadIdx.x, wave = t >> 6, lane = t & 63;
    const int lo = lane & 31, hi = lane >> 5;
    const int qtile = blockIdx.x * 2 + (wave >> 1);
    const int khalf = wave & 1;
    const int b = qtile >> 7, qt = qtile & 127;
    const int qg = qt * 32 + lo;                    // this lane's query column

    FU tb; tb.u[0] = tb.u[1] = tb.u[2] = tb.u[3] = 0;
    if (hi == 0) {
        const float LOG2E = 1.4426950408889634f;
        float tv[8];
#pragma unroll
        for (int j = 0; j < 8; j++)
            tv[j] = theta_g[(((size_t)b * 8 + j) << 12) + qg] * LOG2E;
        tb.u[0] = packbf(tv[0], tv[1]); tb.u[1] = packbf(tv[2], tv[3]);
        tb.u[2] = packbf(tv[4], tv[5]); tb.u[3] = packbf(tv[6], tv[7]);
    }

    fv16 zf, acc;
#pragma unroll
    for (int r = 0; r < 16; r++) { zf[r] = 0.f; acc[r] = 0.f; }
    float ps = 0.f;

    const int kt0 = khalf * 16;
    const unsigned short* phip = phi_pack + ((size_t)((b * 32 + kt0) * 64 + lane)) * 8;
    const unsigned short* gp   = g_pack   + ((size_t)((b * 64 + kt0 * 2) * 64 + lane)) * 8;

#pragma unroll 2
    for (int i = 0; i < 16; i++) {
        FU pa, ga0, ga1;
        pa.v  = *(const bf8*)(phip + (size_t)i * 512);
        ga0.v = *(const bf8*)(gp + (size_t)i * 1024);
        ga1.v = *(const bf8*)(gp + (size_t)i * 1024 + 512);
        fv16 s = __builtin_amdgcn_mfma_f32_32x32x16_bf16(pa.v, tb.v, zf, 0, 0, 0);

        {   // half A: C-regs 0..7 -> PV B-frag for ga0
            unsigned pk[4], qk[4];
#pragma unroll
            for (int u = 0; u < 4; u++) {
                float p0 = __builtin_amdgcn_exp2f(s[2 * u]);
                float p1 = __builtin_amdgcn_exp2f(s[2 * u + 1]);
                ps += p0 + p1;
                pk[u] = packtr(p0, p1);
            }
#pragma unroll
            for (int u = 0; u < 4; u++) qk[u] = (unsigned)__shfl_xor((int)pk[u], 32);
            FU pb;
            pb.u[0] = hi ? qk[2] : pk[0]; pb.u[1] = hi ? qk[3] : pk[1];
            pb.u[2] = hi ? pk[2] : qk[0]; pb.u[3] = hi ? pk[3] : qk[1];
            acc = __builtin_amdgcn_mfma_f32_32x32x16_bf16(ga0.v, pb.v, acc, 0, 0, 0);
        }
        {   // half B: C-regs 8..15 -> PV B-frag for ga1
            unsigned pk[4], qk[4];
#pragma unroll
            for (int u = 0; u < 4; u++) {
                float p0 = __builtin_amdgcn_exp2f(s[8 + 2 * u]);
                float p1 = __builtin_amdgcn_exp2f(s[9 + 2 * u]);
                ps += p0 + p1;
                pk[u] = packtr(p0, p1);
            }
#pragma unroll
            for (int u = 0; u < 4; u++) qk[u] = (unsigned)__shfl_xor((int)pk[u], 32);
            FU pb;
            pb.u[0] = hi ? qk[2] : pk[0]; pb.u[1] = hi ? qk[3] : pk[1];
            pb.u[2] = hi ? pk[2] : qk[0]; pb.u[3] = hi ? pk[3] : qk[1];
            acc = __builtin_amdgcn_mfma_f32_32x32x16_bf16(ga1.v, pb.v, acc, 0, 0, 0);
        }
    }

#pragma unroll
    for (int r = 0; r < 16; r++) comb[wave][lane][r] = acc[r];
    comb[wave][lane][16] = ps;
    __syncthreads();
    const int pw = wave ^ 1;
#pragma unroll
    for (int r = 0; r < 16; r++) acc[r] += comb[pw][lane][r];
    ps += comb[pw][lane][16];

    float lsum = ps + __shfl_xor(ps, 32);
    float inv = 1.f / lsum;

    float on[16];
#pragma unroll
    for (int r = 0; r < 16; r++) on[r] = acc[r] * inv;
    unsigned pk[8], qk[8];
#pragma unroll
    for (int i = 0; i < 8; i++) pk[i] = packtr(on[2 * i], on[2 * i + 1]);
#pragma unroll
    for (int i = 0; i < 8; i++) qk[i] = (unsigned)__shfl_xor((int)pk[i], 32);
    FU ob0, ob1;
    ob0.u[0] = hi ? qk[2] : pk[0]; ob0.u[1] = hi ? qk[3] : pk[1];
    ob0.u[2] = hi ? pk[2] : qk[0]; ob0.u[3] = hi ? pk[3] : qk[1];
    ob1.u[0] = hi ? qk[6] : pk[4]; ob1.u[1] = hi ? qk[7] : pk[5];
    ob1.u[2] = hi ? pk[6] : qk[4]; ob1.u[3] = hi ? pk[7] : qk[5];

    FU wa0, wa1;
    {
        const float* wr = Wa + (khalf * 32 + lo) * 32;
#pragma unroll
        for (int ktw = 0; ktw < 2; ktw++) {
            float w8[8];
#pragma unroll
            for (int j = 0; j < 8; j++) w8[j] = wr[ktw * 16 + hi * 8 + j];
            FU f;
            f.u[0] = packbf(w8[0], w8[1]); f.u[1] = packbf(w8[2], w8[3]);
            f.u[2] = packbf(w8[4], w8[5]); f.u[3] = packbf(w8[6], w8[7]);
            if (ktw == 0) wa0 = f; else wa1 = f;
        }
    }
    fv16 d2 = __builtin_amdgcn_mfma_f32_32x32x16_bf16(wa0.v, ob0.v, zf, 0, 0, 0);
    d2 = __builtin_amdgcn_mfma_f32_32x32x16_bf16(wa1.v, ob1.v, d2, 0, 0, 0);

    const float sig = sigma[0];
#pragma unroll
    for (int r = 0; r < 16; r++) {
        int row = (r & 3) + ((r >> 2) << 3) + (hi << 2);
        int o = khalf * 32 + row;
        size_t idx = (((size_t)b * 64 + o) << 12) + qg;
        out[idx] = x[idx] + sig * d2[r];
    }
}

// ---------------------------------------------------------------------------
extern "C" void kernel_launch(void* const* d_in, const int* in_sizes, int n_in,
                              void* d_out, int out_size, void* d_ws, size_t ws_size,
                              hipStream_t stream) {
    const float* x     = (const float*)d_in[0];
    const float* Wt    = (const float*)d_in[1];
    const float* Wp    = (const float*)d_in[2];
    const float* Wg    = (const float*)d_in[3];
    const float* Wa    = (const float*)d_in[4];
    const float* sigma = (const float*)d_in[5];
    float* out = (float*)d_out;

    // ws layout: theta fp32 (2 MB) | phi_pack bf16 (512 KB) | g_pack bf16 (1 MB)
    float* theta = (float*)d_ws;                                  // 524288 floats
    unsigned short* phi_pack = (unsigned short*)(theta + (size_t)B_ * 8 * HW_);
    unsigned short* g_pack   = phi_pack + (size_t)B_ * 32 * 64 * 8;

    conv_stage<<<512, 256, 0, stream>>>(x, Wt, Wp, Wg, theta, phi_pack, g_pack);
    attn_mfma<<<1024, 256, 0, stream>>>(theta, phi_pack, g_pack, Wa, x, sigma, out);
}